// Round 1
// baseline (8550.098 us; speedup 1.0000x reference)
//
#include <hip/hip_runtime.h>
#include <cstddef>

// MinimalRNNCell: h_T = sum_t x_t @ W @ R^(T-1-t)  (+ h0 @ R^T), output h_T [32,1024].
// Chunked parallel scan (C=64 chunks x L=32 steps) + tree combine with R^(32*2^l).
// All fp32: the recurrence is chaotically sensitive (rho(R)~1.04, 2048 steps) so
// low-precision R is fatal; fp32 reordering error ~1e-4 << 2% threshold.

namespace {

constexpr int BATCH = 32;
constexpr int T = 2048;
constexpr int U = 1024;     // IN_DIM == UNITS == 1024
constexpr int L = 32;       // inner sequential steps
constexpr int C = 64;       // parallel chunks
constexpr int MROWS = C * BATCH;  // 2048 state rows

// ---------------- init: H rows 0..31 = h0 (chunk 0), rest 0 ----------------
__global__ void init_state(const float* __restrict__ h0, float* __restrict__ H) {
    int idx = blockIdx.x * 256 + threadIdx.x;
    if (idx >= MROWS * U) return;
    int r = idx >> 10;
    int u = idx & (U - 1);
    H[idx] = (r < BATCH) ? h0[(r << 10) + u] : 0.0f;
}

// ---------------- step: Hnew = Hold @ R + Xj @ W ----------------
// Xj row r -> x[b = r&31, t = (r>>5)*L + j, :]
constexpr int BM = 128, BN = 64, BK = 16;

__global__ __launch_bounds__(256)
void step_kernel(const float* __restrict__ Hold, float* __restrict__ Hnew,
                 const float* __restrict__ x, const float* __restrict__ R,
                 const float* __restrict__ W, int j)
{
    __shared__ float As[BK][BM];
    __shared__ float Bs[BK][BN];

    const int tid = threadIdx.x;
    const int tx = tid & 15;          // col group 0..15
    const int ty = tid >> 4;          // row group 0..15
    const int row0 = blockIdx.x * BM;
    const int col0 = blockIdx.y * BN;

    // loader indices
    const int la_row = tid >> 2;          // 0..63 (two passes -> 128 rows)
    const int la_k   = (tid & 3) << 2;    // 0,4,8,12
    const int lb_k   = tid >> 4;          // 0..15
    const int lb_col = (tid & 15) << 2;   // 0..60

    float acc[8][4];
    #pragma unroll
    for (int r = 0; r < 8; ++r)
        #pragma unroll
        for (int c = 0; c < 4; ++c) acc[r][c] = 0.0f;

    #pragma unroll 1
    for (int phase = 0; phase < 2; ++phase) {
        const float* __restrict__ Bmat = phase ? W : R;
        #pragma unroll 1
        for (int k0 = 0; k0 < U; k0 += BK) {
            // A tile: 128 rows x 16 k
            #pragma unroll
            for (int p = 0; p < 2; ++p) {
                const int ar = la_row + (p << 6);
                const int grow = row0 + ar;
                const float* aptr;
                if (phase == 0) {
                    aptr = Hold + ((size_t)grow << 10) + k0 + la_k;
                } else {
                    const size_t xrow = (size_t)((grow & 31) * T + ((grow >> 5) * L) + j);
                    aptr = x + (xrow << 10) + k0 + la_k;
                }
                const float4 av = *(const float4*)aptr;
                As[la_k + 0][ar] = av.x;
                As[la_k + 1][ar] = av.y;
                As[la_k + 2][ar] = av.z;
                As[la_k + 3][ar] = av.w;
            }
            // B tile: 16 k x 64 cols
            const float4 bv = *(const float4*)(Bmat + ((size_t)(k0 + lb_k) << 10) + col0 + lb_col);
            *(float4*)&Bs[lb_k][lb_col] = bv;
            __syncthreads();

            #pragma unroll
            for (int kk = 0; kk < BK; ++kk) {
                const float4 b4 = *(const float4*)&Bs[kk][tx << 2];
                const float4 a0 = *(const float4*)&As[kk][ty << 3];
                const float4 a1 = *(const float4*)&As[kk][(ty << 3) + 4];
                const float ar_[8] = {a0.x, a0.y, a0.z, a0.w, a1.x, a1.y, a1.z, a1.w};
                const float bc_[4] = {b4.x, b4.y, b4.z, b4.w};
                #pragma unroll
                for (int r = 0; r < 8; ++r)
                    #pragma unroll
                    for (int c = 0; c < 4; ++c)
                        acc[r][c] = fmaf(ar_[r], bc_[c], acc[r][c]);
            }
            __syncthreads();
        }
    }

    #pragma unroll
    for (int r = 0; r < 8; ++r) {
        const int row = row0 + (ty << 3) + r;
        float4 o;
        o.x = acc[r][0]; o.y = acc[r][1]; o.z = acc[r][2]; o.w = acc[r][3];
        *(float4*)(Hnew + ((size_t)row << 10) + col0 + (tx << 2)) = o;
    }
}

// ---------------- generic matmul: C = A @ B  (N = K = 1024) ----------------
// mode 0: plain (squarings)
// mode 1: tree combine: C[r] = A[gather(r)] @ B + A[gather(r)+32]
//         gather(r) = ((r>>5)<<6) + (r&31)   (even chunk of pair; +32 = odd chunk)
__global__ __launch_bounds__(256)
void matmul_kernel(const float* __restrict__ A, const float* __restrict__ Bm,
                   float* __restrict__ Cm, int M, int mode)
{
    __shared__ float As[16][64];
    __shared__ float Bs[16][64];

    const int tid = threadIdx.x;
    const int tx = tid & 15, ty = tid >> 4;
    const int row0 = blockIdx.x * 64, col0 = blockIdx.y * 64;
    const int la_row = tid >> 2, la_k = (tid & 3) << 2;
    const int lb_k = tid >> 4, lb_col = (tid & 15) << 2;

    float acc[4][4];
    #pragma unroll
    for (int r = 0; r < 4; ++r)
        #pragma unroll
        for (int c = 0; c < 4; ++c) acc[r][c] = 0.0f;

    #pragma unroll 1
    for (int k0 = 0; k0 < U; k0 += 16) {
        const int grow = row0 + la_row;
        float4 av = {0.f, 0.f, 0.f, 0.f};
        if (grow < M) {
            const int arow = (mode == 1) ? (((grow >> 5) << 6) + (grow & 31)) : grow;
            av = *(const float4*)(A + ((size_t)arow << 10) + k0 + la_k);
        }
        As[la_k + 0][la_row] = av.x;
        As[la_k + 1][la_row] = av.y;
        As[la_k + 2][la_row] = av.z;
        As[la_k + 3][la_row] = av.w;
        const float4 bv = *(const float4*)(Bm + ((size_t)(k0 + lb_k) << 10) + col0 + lb_col);
        *(float4*)&Bs[lb_k][lb_col] = bv;
        __syncthreads();

        #pragma unroll
        for (int kk = 0; kk < 16; ++kk) {
            const float4 b4 = *(const float4*)&Bs[kk][tx << 2];
            const float4 a4 = *(const float4*)&As[kk][ty << 2];
            const float ar_[4] = {a4.x, a4.y, a4.z, a4.w};
            const float bc_[4] = {b4.x, b4.y, b4.z, b4.w};
            #pragma unroll
            for (int r = 0; r < 4; ++r)
                #pragma unroll
                for (int c = 0; c < 4; ++c)
                    acc[r][c] = fmaf(ar_[r], bc_[c], acc[r][c]);
        }
        __syncthreads();
    }

    #pragma unroll
    for (int r = 0; r < 4; ++r) {
        const int row = row0 + (ty << 2) + r;
        if (row < M) {
            float4 o;
            o.x = acc[r][0]; o.y = acc[r][1]; o.z = acc[r][2]; o.w = acc[r][3];
            if (mode == 1) {
                const int addrow = ((row >> 5) << 6) + (row & 31) + 32;
                const float4 ad = *(const float4*)(A + ((size_t)addrow << 10) + col0 + (tx << 2));
                o.x += ad.x; o.y += ad.y; o.z += ad.z; o.w += ad.w;
            }
            *(float4*)(Cm + ((size_t)row << 10) + col0 + (tx << 2)) = o;
        }
    }
}

} // namespace

extern "C" void kernel_launch(void* const* d_in, const int* in_sizes, int n_in,
                              void* d_out, int out_size, void* d_ws, size_t ws_size,
                              hipStream_t stream) {
    const float* x  = (const float*)d_in[0];   // [32, 2048, 1024]
    const float* h0 = (const float*)d_in[1];   // [32, 1024]
    const float* W  = (const float*)d_in[2];   // [1024, 1024]
    const float* R  = (const float*)d_in[3];   // [1024, 1024]
    float* out = (float*)d_out;                // [32, 1024]

    float* H0 = (float*)d_ws;                  // 8 MB
    float* H1 = H0 + (size_t)MROWS * U;        // 8 MB
    float* QA = H1 + (size_t)MROWS * U;        // 4 MB
    float* QB = QA + (size_t)U * U;            // 4 MB  (total 24 MB of ws)

    // 1) init chunked state
    init_state<<<(MROWS * U + 255) / 256, 256, 0, stream>>>(h0, H0);

    // 2) 32 inner steps over all 64 chunks in parallel
    float* cur = H0;
    float* nxt = H1;
    dim3 sgrid(MROWS / BM, U / BN);  // (16, 16)
    for (int j = 0; j < L; ++j) {
        step_kernel<<<sgrid, 256, 0, stream>>>(cur, nxt, x, R, W, j);
        float* t = cur; cur = nxt; nxt = t;
    }

    // 3) Q = R^32 via 5 squarings
    dim3 qgrid(U / 64, U / 64);      // (16, 16)
    matmul_kernel<<<qgrid, 256, 0, stream>>>(R,  R,  QA, U, 0);  // R^2
    matmul_kernel<<<qgrid, 256, 0, stream>>>(QA, QA, QB, U, 0);  // R^4
    matmul_kernel<<<qgrid, 256, 0, stream>>>(QB, QB, QA, U, 0);  // R^8
    matmul_kernel<<<qgrid, 256, 0, stream>>>(QA, QA, QB, U, 0);  // R^16
    matmul_kernel<<<qgrid, 256, 0, stream>>>(QB, QB, QA, U, 0);  // R^32
    float* q = QA;
    float* qn = QB;

    // 4) tree combine: 6 levels, g'_i = g_{2i} @ Q + g_{2i+1}; Q <- Q^2
    for (int lev = 0; lev < 6; ++lev) {
        const int npairs = 32 >> lev;
        const int M = npairs * 32;
        float* dst = (lev == 5) ? out : nxt;
        dim3 cgrid((M + 63) / 64, U / 64);
        matmul_kernel<<<cgrid, 256, 0, stream>>>(cur, q, dst, M, 1);
        if (lev < 5) {
            matmul_kernel<<<qgrid, 256, 0, stream>>>(q, q, qn, U, 0);
            float* t = q; q = qn; qn = t;
        }
        float* t = cur; cur = nxt; nxt = t;
    }
    (void)in_sizes; (void)n_in; (void)out_size; (void)ws_size;
}

// Round 2
// 4975.884 us; speedup vs baseline: 1.7183x; 1.7183x over previous
//
#include <hip/hip_runtime.h>
#include <cstddef>

// MinimalRNNCell: h_T = sum_t x_t @ W @ R^(T-1-t) (+ h0 @ R^T), output h_T [32,1024].
// Chunked parallel scan: C=128 chunks x L=16 steps, then 7-level tree combine with
// Q = R^(16*2^l). All fp32 (rho(R)~1.04 over 2048 steps => low-precision R fatal).
//
// R2 changes vs R1 (theory: latency-bound, 1 block/CU, 4-way LDS conflicts):
//  - C 64->128: grid for step GEMM becomes 1024 blocks = 4 blocks/CU (occupancy 12->50%)
//  - conflict-free LDS: A stored transposed with row=tid&63 (2-way = free), compute
//    reads are 16-lane broadcasts
//  - double-buffered LDS, single barrier per K-tile, global prefetch under compute

namespace {

constexpr int BATCH = 32;
constexpr int T = 2048;
constexpr int U = 1024;
constexpr int L = 16;           // sequential steps
constexpr int C = 128;          // parallel chunks
constexpr int MROWS = C * BATCH; // 4096

__global__ void init_state(const float* __restrict__ h0, float* __restrict__ H) {
    int idx = blockIdx.x * 256 + threadIdx.x;
    if (idx >= MROWS * U) return;
    int r = idx >> 10;
    int u = idx & (U - 1);
    H[idx] = (r < BATCH) ? h0[(r << 10) + u] : 0.0f;
}

// ---------------- step: Hnew[4096,1024] = Hold @ R + Xj @ W (fused K=2048) --------
// Xj row r -> x[b = r&31, t = (r>>5)*L + j, :]
__global__ __launch_bounds__(256, 2)
void step_kernel(const float* __restrict__ Hold, float* __restrict__ Hnew,
                 const float* __restrict__ x, const float* __restrict__ R,
                 const float* __restrict__ W, int j)
{
    __shared__ float As[2][16][64];   // [buf][k][row]  (transposed)
    __shared__ float Bs[2][16][64];   // [buf][k][col]

    const int tid = threadIdx.x;
    const int tx = tid & 15;          // col group (4 cols)
    const int ty = tid >> 4;          // row group (4 rows)
    const int row0 = blockIdx.x * 64;
    const int col0 = blockIdx.y * 64;

    // loaders
    const int la_row = tid & 63;          // A: one float4 of row la_row
    const int la_k   = (tid >> 6) << 2;   // k offset 0/4/8/12
    const int lb_k   = tid >> 4;          // B: row k = lb_k
    const int lb_col = (tid & 15) << 2;

    const int arow = row0 + la_row;
    const float* aR = Hold + ((size_t)arow << 10) + la_k;
    const size_t xrow = (size_t)(arow & 31) * T + (size_t)(arow >> 5) * L + (size_t)j;
    const float* aW = x + (xrow << 10) + la_k;
    const float* bR = R + ((size_t)lb_k << 10) + col0 + lb_col;
    const float* bW = W + ((size_t)lb_k << 10) + col0 + lb_col;

    float acc[4][4];
    #pragma unroll
    for (int r = 0; r < 4; ++r)
        #pragma unroll
        for (int c = 0; c < 4; ++c) acc[r][c] = 0.0f;

    // prologue: tile 0 (phase R, k0 = 0)
    {
        const float4 av = *(const float4*)aR;
        const float4 bv = *(const float4*)bR;
        As[0][la_k + 0][la_row] = av.x;
        As[0][la_k + 1][la_row] = av.y;
        As[0][la_k + 2][la_row] = av.z;
        As[0][la_k + 3][la_row] = av.w;
        *(float4*)&Bs[0][lb_k][lb_col] = bv;
    }
    __syncthreads();

    int buf = 0;
    #pragma unroll 1
    for (int kt = 0; kt < 128; ++kt) {
        float4 an, bn;
        const bool more = (kt < 127);
        if (more) {
            const int ktn = kt + 1;
            const int k0 = (ktn & 63) << 4;
            const float* ap = (ktn < 64 ? aR : aW) + k0;
            const float* bp = (ktn < 64 ? bR : bW) + ((size_t)k0 << 10);
            an = *(const float4*)ap;
            bn = *(const float4*)bp;
        }

        #pragma unroll
        for (int kk = 0; kk < 16; ++kk) {
            const float4 a4 = *(const float4*)&As[buf][kk][ty << 2];
            const float4 b4 = *(const float4*)&Bs[buf][kk][tx << 2];
            const float ar_[4] = {a4.x, a4.y, a4.z, a4.w};
            const float bc_[4] = {b4.x, b4.y, b4.z, b4.w};
            #pragma unroll
            for (int r = 0; r < 4; ++r)
                #pragma unroll
                for (int c = 0; c < 4; ++c)
                    acc[r][c] = fmaf(ar_[r], bc_[c], acc[r][c]);
        }

        if (more) {
            As[buf ^ 1][la_k + 0][la_row] = an.x;
            As[buf ^ 1][la_k + 1][la_row] = an.y;
            As[buf ^ 1][la_k + 2][la_row] = an.z;
            As[buf ^ 1][la_k + 3][la_row] = an.w;
            *(float4*)&Bs[buf ^ 1][lb_k][lb_col] = bn;
        }
        __syncthreads();
        buf ^= 1;
    }

    #pragma unroll
    for (int r = 0; r < 4; ++r) {
        const int row = row0 + (ty << 2) + r;
        float4 o;
        o.x = acc[r][0]; o.y = acc[r][1]; o.z = acc[r][2]; o.w = acc[r][3];
        *(float4*)(Hnew + ((size_t)row << 10) + col0 + (tx << 2)) = o;
    }
}

// ---------------- generic matmul: C = A @ B (N = K = 1024) ----------------
// mode 0: plain (squarings). mode 1: tree combine C[r] = A[g(r)] @ B + A[g(r)+32],
//         g(r) = ((r>>5)<<6) + (r&31).
__global__ __launch_bounds__(256, 2)
void matmul_kernel(const float* __restrict__ A, const float* __restrict__ Bm,
                   float* __restrict__ Cm, int M, int mode)
{
    __shared__ float As[2][16][64];
    __shared__ float Bs[2][16][64];

    const int tid = threadIdx.x;
    const int tx = tid & 15, ty = tid >> 4;
    const int row0 = blockIdx.x * 64, col0 = blockIdx.y * 64;
    const int la_row = tid & 63, la_k = (tid >> 6) << 2;
    const int lb_k = tid >> 4, lb_col = (tid & 15) << 2;

    const int grow = row0 + la_row;
    const int arow = (mode == 1) ? (((grow >> 5) << 6) + (grow & 31)) : grow;
    const bool aval = (grow < M);
    const float* aP = A + ((size_t)arow << 10) + la_k;
    const float* bP = Bm + ((size_t)lb_k << 10) + col0 + lb_col;

    float acc[4][4];
    #pragma unroll
    for (int r = 0; r < 4; ++r)
        #pragma unroll
        for (int c = 0; c < 4; ++c) acc[r][c] = 0.0f;

    {
        float4 av = {0.f, 0.f, 0.f, 0.f};
        if (aval) av = *(const float4*)aP;
        const float4 bv = *(const float4*)bP;
        As[0][la_k + 0][la_row] = av.x;
        As[0][la_k + 1][la_row] = av.y;
        As[0][la_k + 2][la_row] = av.z;
        As[0][la_k + 3][la_row] = av.w;
        *(float4*)&Bs[0][lb_k][lb_col] = bv;
    }
    __syncthreads();

    int buf = 0;
    #pragma unroll 1
    for (int kt = 0; kt < 64; ++kt) {
        float4 an = {0.f, 0.f, 0.f, 0.f};
        float4 bn;
        const bool more = (kt < 63);
        if (more) {
            const int k0 = (kt + 1) << 4;
            if (aval) an = *(const float4*)(aP + k0);
            bn = *(const float4*)(bP + ((size_t)k0 << 10));
        }

        #pragma unroll
        for (int kk = 0; kk < 16; ++kk) {
            const float4 a4 = *(const float4*)&As[buf][kk][ty << 2];
            const float4 b4 = *(const float4*)&Bs[buf][kk][tx << 2];
            const float ar_[4] = {a4.x, a4.y, a4.z, a4.w};
            const float bc_[4] = {b4.x, b4.y, b4.z, b4.w};
            #pragma unroll
            for (int r = 0; r < 4; ++r)
                #pragma unroll
                for (int c = 0; c < 4; ++c)
                    acc[r][c] = fmaf(ar_[r], bc_[c], acc[r][c]);
        }

        if (more) {
            As[buf ^ 1][la_k + 0][la_row] = an.x;
            As[buf ^ 1][la_k + 1][la_row] = an.y;
            As[buf ^ 1][la_k + 2][la_row] = an.z;
            As[buf ^ 1][la_k + 3][la_row] = an.w;
            *(float4*)&Bs[buf ^ 1][lb_k][lb_col] = bn;
        }
        __syncthreads();
        buf ^= 1;
    }

    #pragma unroll
    for (int r = 0; r < 4; ++r) {
        const int row = row0 + (ty << 2) + r;
        if (row < M) {
            float4 o;
            o.x = acc[r][0]; o.y = acc[r][1]; o.z = acc[r][2]; o.w = acc[r][3];
            if (mode == 1) {
                const int addrow = ((row >> 5) << 6) + (row & 31) + 32;
                const float4 ad = *(const float4*)(A + ((size_t)addrow << 10) + col0 + (tx << 2));
                o.x += ad.x; o.y += ad.y; o.z += ad.z; o.w += ad.w;
            }
            *(float4*)(Cm + ((size_t)row << 10) + col0 + (tx << 2)) = o;
        }
    }
}

} // namespace

extern "C" void kernel_launch(void* const* d_in, const int* in_sizes, int n_in,
                              void* d_out, int out_size, void* d_ws, size_t ws_size,
                              hipStream_t stream) {
    const float* x  = (const float*)d_in[0];   // [32, 2048, 1024]
    const float* h0 = (const float*)d_in[1];   // [32, 1024]
    const float* W  = (const float*)d_in[2];   // [1024, 1024]
    const float* R  = (const float*)d_in[3];   // [1024, 1024]
    float* out = (float*)d_out;                // [32, 1024]

    float* H0 = (float*)d_ws;                  // 16 MB
    float* H1 = H0 + (size_t)MROWS * U;        // 16 MB
    float* QA = H1 + (size_t)MROWS * U;        // 4 MB
    float* QB = QA + (size_t)U * U;            // 4 MB  (40 MB total)

    // 1) init chunked state (chunk 0 rows carry h0)
    init_state<<<(MROWS * U + 255) / 256, 256, 0, stream>>>(h0, H0);

    // 2) L sequential steps over all chunks in parallel
    float* cur = H0;
    float* nxt = H1;
    dim3 sgrid(MROWS / 64, U / 64);   // (64, 16) = 1024 blocks
    for (int j = 0; j < L; ++j) {
        step_kernel<<<sgrid, 256, 0, stream>>>(cur, nxt, x, R, W, j);
        float* t = cur; cur = nxt; nxt = t;
    }

    // 3) Q = R^16 via 4 squarings
    dim3 qgrid(U / 64, U / 64);       // (16, 16)
    matmul_kernel<<<qgrid, 256, 0, stream>>>(R,  R,  QA, U, 0);  // R^2
    matmul_kernel<<<qgrid, 256, 0, stream>>>(QA, QA, QB, U, 0);  // R^4
    matmul_kernel<<<qgrid, 256, 0, stream>>>(QB, QB, QA, U, 0);  // R^8
    matmul_kernel<<<qgrid, 256, 0, stream>>>(QA, QA, QB, U, 0);  // R^16
    float* q = QB;
    float* qn = QA;

    // 4) tree combine: 7 levels, g'_i = g_{2i} @ Q + g_{2i+1}; Q <- Q^2
    for (int lev = 0; lev < 7; ++lev) {
        const int npairs = (C / 2) >> lev;        // 64, 32, ..., 1
        const int M = npairs * BATCH;
        float* dst = (lev == 6) ? out : nxt;
        dim3 cgrid((M + 63) / 64, U / 64);
        matmul_kernel<<<cgrid, 256, 0, stream>>>(cur, q, dst, M, 1);
        if (lev < 6) {
            matmul_kernel<<<qgrid, 256, 0, stream>>>(q, q, qn, U, 0);
            float* t = q; q = qn; qn = t;
        }
        float* t = cur; cur = nxt; nxt = t;
    }
    (void)in_sizes; (void)n_in; (void)out_size; (void)ws_size;
}

// Round 3
// 3221.502 us; speedup vs baseline: 2.6541x; 1.5446x over previous
//
#include <hip/hip_runtime.h>
#include <cstddef>

// MinimalRNNCell h_T: purely linear scan =>
//   g_c = sum_{i<8} x_{8c+i} @ (W R^{7-i})  -- ONE parallel GEMM with stacked G
//   tree-combine chunk aggregates with Q_l = R^(8*2^l); h0 injected into chunk 0.
// All fp32: rho(R)~1.038 over 2048 steps makes low-precision weights fatal;
// fp32 reorder error measured ~8e31 vs 6.7e32 threshold.

namespace {

constexpr int BATCH = 32;
constexpr int T = 2048;
constexpr int U = 1024;

// ---------------- primary path: chunk length 8 ----------------
constexpr int LJ = 8;               // chunk length
constexpr int CJ = T / LJ;          // 256 chunks
constexpr int MJ = CJ * BATCH;      // 8192 aggregate rows

struct Desc {
    const float* A;
    const float* B;
    float* C;
    int M;
    int K;
    int mode;   // 0: C=A@B   1: A = x-gather (main)   2: C+=A@B   3: tree combine
};

// 128x64 tile, 256 threads, 8x4 microtile, double-buffered LDS.
__global__ __launch_bounds__(256, 2)
void gemm128(Desc d0, Desc d1)
{
    Desc d = (blockIdx.z == 0) ? d0 : d1;
    const int row0 = blockIdx.x * 128;
    if (row0 >= d.M) return;            // whole block exits (dummy z / tail)
    const int col0 = blockIdx.y * 64;

    __shared__ float As[2][16][128];    // [buf][k][row] transposed
    __shared__ float Bs[2][16][64];     // [buf][k][col]

    const int tid = threadIdx.x;
    const int tx = tid & 15;            // col group (4 cols)
    const int ty = tid >> 4;            // row group (8 rows)
    const int la_row = tid & 127;
    const int la_k   = (tid >> 7) << 3; // 0 or 8
    const int lb_k   = tid >> 4;        // 0..15
    const int lb_c   = (tid & 15) << 2;

    int ar = row0 + la_row;
    if (ar >= d.M) ar = d.M - 1;        // clamp for tails (values unused)
    const float* aP;
    if (d.mode == 1) {
        // row r -> chunk c=r>>5, batch b=r&31; A'row = x[b, c*LJ : (c+1)*LJ, :]
        // contiguous: addr = ((b*T + c*LJ) << 10) + k   (t-stride == feature dim)
        aP = d.A + ((size_t)((ar & 31) * T + ((ar >> 5) * LJ)) << 10);
    } else if (d.mode == 3) {
        aP = d.A + ((size_t)(((ar >> 5) << 6) + (ar & 31)) << 10);
    } else {
        aP = d.A + ((size_t)ar << 10);
    }
    aP += la_k;
    const float* bP = d.B + ((size_t)lb_k << 10) + col0 + lb_c;

    float acc[8][4];
    #pragma unroll
    for (int r = 0; r < 8; ++r)
        #pragma unroll
        for (int c = 0; c < 4; ++c) acc[r][c] = 0.0f;

    // prologue: stage K-tile 0
    {
        const float4 a0 = *(const float4*)(aP);
        const float4 a1 = *(const float4*)(aP + 4);
        const float4 b0 = *(const float4*)(bP);
        As[0][la_k+0][la_row]=a0.x; As[0][la_k+1][la_row]=a0.y;
        As[0][la_k+2][la_row]=a0.z; As[0][la_k+3][la_row]=a0.w;
        As[0][la_k+4][la_row]=a1.x; As[0][la_k+5][la_row]=a1.y;
        As[0][la_k+6][la_row]=a1.z; As[0][la_k+7][la_row]=a1.w;
        *(float4*)&Bs[0][lb_k][lb_c] = b0;
    }
    __syncthreads();

    const int NT = d.K >> 4;
    int buf = 0;
    #pragma unroll 1
    for (int kt = 0; kt < NT; ++kt) {
        float4 na0, na1, nb0;
        const bool more = (kt + 1 < NT);
        if (more) {
            const float* ap = aP + ((kt + 1) << 4);
            na0 = *(const float4*)(ap);
            na1 = *(const float4*)(ap + 4);
            nb0 = *(const float4*)(bP + ((size_t)((kt + 1) << 4) << 10));
        }

        #pragma unroll
        for (int kk = 0; kk < 16; ++kk) {
            const float4 a0 = *(const float4*)&As[buf][kk][ty << 3];
            const float4 a1 = *(const float4*)&As[buf][kk][(ty << 3) + 4];
            const float4 bv = *(const float4*)&Bs[buf][kk][tx << 2];
            const float ar8[8] = {a0.x,a0.y,a0.z,a0.w,a1.x,a1.y,a1.z,a1.w};
            const float bc4[4] = {bv.x,bv.y,bv.z,bv.w};
            #pragma unroll
            for (int r = 0; r < 8; ++r)
                #pragma unroll
                for (int c = 0; c < 4; ++c)
                    acc[r][c] = fmaf(ar8[r], bc4[c], acc[r][c]);
        }

        if (more) {
            As[buf^1][la_k+0][la_row]=na0.x; As[buf^1][la_k+1][la_row]=na0.y;
            As[buf^1][la_k+2][la_row]=na0.z; As[buf^1][la_k+3][la_row]=na0.w;
            As[buf^1][la_k+4][la_row]=na1.x; As[buf^1][la_k+5][la_row]=na1.y;
            As[buf^1][la_k+6][la_row]=na1.z; As[buf^1][la_k+7][la_row]=na1.w;
            *(float4*)&Bs[buf^1][lb_k][lb_c] = nb0;
        }
        __syncthreads();
        buf ^= 1;
    }

    #pragma unroll
    for (int r = 0; r < 8; ++r) {
        const int row = row0 + (ty << 3) + r;
        if (row < d.M) {
            float4 o;
            o.x = acc[r][0]; o.y = acc[r][1]; o.z = acc[r][2]; o.w = acc[r][3];
            float* cp = d.C + ((size_t)row << 10) + col0 + (tx << 2);
            if (d.mode == 2) {
                const float4 cv = *(const float4*)cp;
                o.x += cv.x; o.y += cv.y; o.z += cv.z; o.w += cv.w;
            } else if (d.mode == 3) {
                const int arow2 = ((row >> 5) << 6) + (row & 31) + 32;
                const float4 ad = *(const float4*)(d.A + ((size_t)arow2 << 10) + col0 + (tx << 2));
                o.x += ad.x; o.y += ad.y; o.z += ad.z; o.w += ad.w;
            }
            *(float4*)cp = o;
        }
    }
}

// ================= fallback path (R2, proven) — used if ws too small =========
constexpr int FB_L = 16;
constexpr int FB_C = 128;
constexpr int FB_MROWS = FB_C * BATCH;   // 4096

__global__ void init_state(const float* __restrict__ h0, float* __restrict__ H) {
    int idx = blockIdx.x * 256 + threadIdx.x;
    if (idx >= FB_MROWS * U) return;
    int r = idx >> 10;
    int u = idx & (U - 1);
    H[idx] = (r < BATCH) ? h0[(r << 10) + u] : 0.0f;
}

__global__ __launch_bounds__(256, 2)
void step_kernel(const float* __restrict__ Hold, float* __restrict__ Hnew,
                 const float* __restrict__ x, const float* __restrict__ R,
                 const float* __restrict__ W, int j)
{
    __shared__ float As[2][16][64];
    __shared__ float Bs[2][16][64];

    const int tid = threadIdx.x;
    const int tx = tid & 15;
    const int ty = tid >> 4;
    const int row0 = blockIdx.x * 64;
    const int col0 = blockIdx.y * 64;

    const int la_row = tid & 63;
    const int la_k   = (tid >> 6) << 2;
    const int lb_k   = tid >> 4;
    const int lb_col = (tid & 15) << 2;

    const int arow = row0 + la_row;
    const float* aR = Hold + ((size_t)arow << 10) + la_k;
    const size_t xrow = (size_t)(arow & 31) * T + (size_t)(arow >> 5) * FB_L + (size_t)j;
    const float* aW = x + (xrow << 10) + la_k;
    const float* bR = R + ((size_t)lb_k << 10) + col0 + lb_col;
    const float* bW = W + ((size_t)lb_k << 10) + col0 + lb_col;

    float acc[4][4];
    #pragma unroll
    for (int r = 0; r < 4; ++r)
        #pragma unroll
        for (int c = 0; c < 4; ++c) acc[r][c] = 0.0f;

    {
        const float4 av = *(const float4*)aR;
        const float4 bv = *(const float4*)bR;
        As[0][la_k + 0][la_row] = av.x;
        As[0][la_k + 1][la_row] = av.y;
        As[0][la_k + 2][la_row] = av.z;
        As[0][la_k + 3][la_row] = av.w;
        *(float4*)&Bs[0][lb_k][lb_col] = bv;
    }
    __syncthreads();

    int buf = 0;
    #pragma unroll 1
    for (int kt = 0; kt < 128; ++kt) {
        float4 an, bn;
        const bool more = (kt < 127);
        if (more) {
            const int ktn = kt + 1;
            const int k0 = (ktn & 63) << 4;
            const float* ap = (ktn < 64 ? aR : aW) + k0;
            const float* bp = (ktn < 64 ? bR : bW) + ((size_t)k0 << 10);
            an = *(const float4*)ap;
            bn = *(const float4*)bp;
        }
        #pragma unroll
        for (int kk = 0; kk < 16; ++kk) {
            const float4 a4 = *(const float4*)&As[buf][kk][ty << 2];
            const float4 b4 = *(const float4*)&Bs[buf][kk][tx << 2];
            const float ar_[4] = {a4.x, a4.y, a4.z, a4.w};
            const float bc_[4] = {b4.x, b4.y, b4.z, b4.w};
            #pragma unroll
            for (int r = 0; r < 4; ++r)
                #pragma unroll
                for (int c = 0; c < 4; ++c)
                    acc[r][c] = fmaf(ar_[r], bc_[c], acc[r][c]);
        }
        if (more) {
            As[buf ^ 1][la_k + 0][la_row] = an.x;
            As[buf ^ 1][la_k + 1][la_row] = an.y;
            As[buf ^ 1][la_k + 2][la_row] = an.z;
            As[buf ^ 1][la_k + 3][la_row] = an.w;
            *(float4*)&Bs[buf ^ 1][lb_k][lb_col] = bn;
        }
        __syncthreads();
        buf ^= 1;
    }

    #pragma unroll
    for (int r = 0; r < 4; ++r) {
        const int row = row0 + (ty << 2) + r;
        float4 o;
        o.x = acc[r][0]; o.y = acc[r][1]; o.z = acc[r][2]; o.w = acc[r][3];
        *(float4*)(Hnew + ((size_t)row << 10) + col0 + (tx << 2)) = o;
    }
}

__global__ __launch_bounds__(256, 2)
void matmul_kernel(const float* __restrict__ A, const float* __restrict__ Bm,
                   float* __restrict__ Cm, int M, int mode)
{
    __shared__ float As[2][16][64];
    __shared__ float Bs[2][16][64];

    const int tid = threadIdx.x;
    const int tx = tid & 15, ty = tid >> 4;
    const int row0 = blockIdx.x * 64, col0 = blockIdx.y * 64;
    const int la_row = tid & 63, la_k = (tid >> 6) << 2;
    const int lb_k = tid >> 4, lb_col = (tid & 15) << 2;

    const int grow = row0 + la_row;
    const int arow = (mode == 1) ? (((grow >> 5) << 6) + (grow & 31)) : grow;
    const bool aval = (grow < M);
    const float* aP = A + ((size_t)arow << 10) + la_k;
    const float* bP = Bm + ((size_t)lb_k << 10) + col0 + lb_col;

    float acc[4][4];
    #pragma unroll
    for (int r = 0; r < 4; ++r)
        #pragma unroll
        for (int c = 0; c < 4; ++c) acc[r][c] = 0.0f;

    {
        float4 av = {0.f, 0.f, 0.f, 0.f};
        if (aval) av = *(const float4*)aP;
        const float4 bv = *(const float4*)bP;
        As[0][la_k + 0][la_row] = av.x;
        As[0][la_k + 1][la_row] = av.y;
        As[0][la_k + 2][la_row] = av.z;
        As[0][la_k + 3][la_row] = av.w;
        *(float4*)&Bs[0][lb_k][lb_col] = bv;
    }
    __syncthreads();

    int buf = 0;
    #pragma unroll 1
    for (int kt = 0; kt < 64; ++kt) {
        float4 an = {0.f, 0.f, 0.f, 0.f};
        float4 bn;
        const bool more = (kt < 63);
        if (more) {
            const int k0 = (kt + 1) << 4;
            if (aval) an = *(const float4*)(aP + k0);
            bn = *(const float4*)(bP + ((size_t)k0 << 10));
        }
        #pragma unroll
        for (int kk = 0; kk < 16; ++kk) {
            const float4 a4 = *(const float4*)&As[buf][kk][ty << 2];
            const float4 b4 = *(const float4*)&Bs[buf][kk][tx << 2];
            const float ar_[4] = {a4.x, a4.y, a4.z, a4.w};
            const float bc_[4] = {b4.x, b4.y, b4.z, b4.w};
            #pragma unroll
            for (int r = 0; r < 4; ++r)
                #pragma unroll
                for (int c = 0; c < 4; ++c)
                    acc[r][c] = fmaf(ar_[r], bc_[c], acc[r][c]);
        }
        if (more) {
            As[buf ^ 1][la_k + 0][la_row] = an.x;
            As[buf ^ 1][la_k + 1][la_row] = an.y;
            As[buf ^ 1][la_k + 2][la_row] = an.z;
            As[buf ^ 1][la_k + 3][la_row] = an.w;
            *(float4*)&Bs[buf ^ 1][lb_k][lb_col] = bn;
        }
        __syncthreads();
        buf ^= 1;
    }

    #pragma unroll
    for (int r = 0; r < 4; ++r) {
        const int row = row0 + (ty << 2) + r;
        if (row < M) {
            float4 o;
            o.x = acc[r][0]; o.y = acc[r][1]; o.z = acc[r][2]; o.w = acc[r][3];
            if (mode == 1) {
                const int addrow = ((row >> 5) << 6) + (row & 31) + 32;
                const float4 ad = *(const float4*)(A + ((size_t)addrow << 10) + col0 + (tx << 2));
                o.x += ad.x; o.y += ad.y; o.z += ad.z; o.w += ad.w;
            }
            *(float4*)(Cm + ((size_t)row << 10) + col0 + (tx << 2)) = o;
        }
    }
}

} // namespace

extern "C" void kernel_launch(void* const* d_in, const int* in_sizes, int n_in,
                              void* d_out, int out_size, void* d_ws, size_t ws_size,
                              hipStream_t stream) {
    const float* x  = (const float*)d_in[0];   // [32, 2048, 1024]
    const float* h0 = (const float*)d_in[1];   // [32, 1024]
    const float* W  = (const float*)d_in[2];   // [1024, 1024]
    const float* R  = (const float*)d_in[3];   // [1024, 1024]
    float* out = (float*)d_out;                // [32, 1024]

    const size_t G_f  = (size_t)LJ * U * U;        // 8M floats (32 MB)
    const size_t g0_f = (size_t)MJ * U;            // 8M floats (32 MB)
    const size_t g1_f = (size_t)(MJ / 2) * U;      // 4M floats (16 MB)
    const size_t q_f  = (size_t)U * U;             // 1M floats (4 MB)
    const size_t need = (G_f + g0_f + g1_f + 2 * q_f) * sizeof(float);  // ~88 MB

    if (ws_size >= need) {
        float* G  = (float*)d_ws;
        float* g0 = G + G_f;
        float* g1 = g0 + g0_f;
        float* QA = g1 + g1_f;
        float* QB = QA + q_f;
        auto Gs = [&](int s) { return G + (size_t)s * U * U; };

        Desc dz; dz.A = nullptr; dz.B = nullptr; dz.C = nullptr; dz.M = 0; dz.K = 16; dz.mode = 0;
        auto launch2 = [&](Desc a, Desc b) {
            const int mx = (a.M > b.M) ? a.M : b.M;
            dim3 grid((unsigned)((mx + 127) / 128), (unsigned)(U / 64), 2);
            gemm128<<<grid, dim3(256), 0, stream>>>(a, b);
        };
        auto D = [](const float* A, const float* B, float* C, int M, int K, int mode) {
            Desc d; d.A = A; d.B = B; d.C = C; d.M = M; d.K = K; d.mode = mode; return d;
        };

        // G segment s holds W @ R^(LJ-1-s); seg7 = W
        hipMemcpyAsync(Gs(LJ - 1), W, (size_t)U * U * sizeof(float),
                       hipMemcpyDeviceToDevice, stream);
        // builds (z0) fused with R-power squarings (z1)
        launch2(D(Gs(7), R,  Gs(6), U,     U, 0), D(R,  R,  QA, U, U, 0));  // WR ; R2
        launch2(D(Gs(6), QA, Gs(4), 2 * U, U, 0), D(QA, QA, QB, U, U, 0));  // WR2,WR3 ; R4
        launch2(D(Gs(4), QB, Gs(0), 4 * U, U, 0), D(QB, QB, QA, U, U, 0));  // WR4..7 ; R8

        // main: g0[8192,1024] = Xgather[8192, 8192] @ G
        launch2(D(x, G, g0, MJ, LJ * U, 1), dz);

        // inject h0: g0[0:32] += h0 @ R^8  (QA)
        launch2(D(h0, QA, g0, BATCH, U, 2), dz);

        // tree combine: 8 levels, Q_l = R^(8*2^l) starting at QA = R^8
        float* q  = QA;
        float* qn = QB;
        float* cur = g0;
        float* nxt = g1;
        for (int l = 0; l < 8; ++l) {
            const int M = BATCH * ((CJ / 2) >> l);    // 4096 ... 32
            float* dst = (l == 7) ? out : nxt;
            Desc dc = D(cur, q, dst, M, U, 3);
            Desc ds = dz;
            if (l < 7) ds = D(q, q, qn, U, U, 0);
            launch2(dc, ds);
            if (l < 7) { float* t = q; q = qn; qn = t; }
            float* t2 = cur; cur = nxt; nxt = t2;
        }
    } else {
        // ---------------- fallback: proven R2 path (needs 40 MB) ----------------
        float* H0 = (float*)d_ws;
        float* H1 = H0 + (size_t)FB_MROWS * U;
        float* QA = H1 + (size_t)FB_MROWS * U;
        float* QB = QA + (size_t)U * U;

        init_state<<<(FB_MROWS * U + 255) / 256, 256, 0, stream>>>(h0, H0);

        float* cur = H0;
        float* nxt = H1;
        dim3 sgrid(FB_MROWS / 64, U / 64);
        for (int j = 0; j < FB_L; ++j) {
            step_kernel<<<sgrid, 256, 0, stream>>>(cur, nxt, x, R, W, j);
            float* t = cur; cur = nxt; nxt = t;
        }

        dim3 qgrid(U / 64, U / 64);
        matmul_kernel<<<qgrid, 256, 0, stream>>>(R,  R,  QA, U, 0);
        matmul_kernel<<<qgrid, 256, 0, stream>>>(QA, QA, QB, U, 0);
        matmul_kernel<<<qgrid, 256, 0, stream>>>(QB, QB, QA, U, 0);
        matmul_kernel<<<qgrid, 256, 0, stream>>>(QA, QA, QB, U, 0);
        float* q = QB;
        float* qn = QA;

        for (int lev = 0; lev < 7; ++lev) {
            const int npairs = (FB_C / 2) >> lev;
            const int M = npairs * BATCH;
            float* dst = (lev == 6) ? out : nxt;
            dim3 cgrid((M + 63) / 64, U / 64);
            matmul_kernel<<<cgrid, 256, 0, stream>>>(cur, q, dst, M, 1);
            if (lev < 6) {
                matmul_kernel<<<qgrid, 256, 0, stream>>>(q, q, qn, U, 0);
                float* t = q; q = qn; qn = t;
            }
            float* t = cur; cur = nxt; nxt = t;
        }
    }
    (void)in_sizes; (void)n_in; (void)out_size; (void)ws_size;
}

// Round 4
// 1927.500 us; speedup vs baseline: 4.4358x; 1.6713x over previous
//
#include <hip/hip_runtime.h>
#include <cstddef>
#include <cstdint>

// MinimalRNNCell h_T: purely linear scan.
//   g_c = sum_{i<8} x_{8c+i} @ (W R^{7-i})  -- ONE parallel GEMM (x-gather @ stacked G)
//   tree-combine chunk aggregates with Q_l = R^(8*2^l); h0 injected into chunk 0.
// R4: main GEMM on MFMA via fp16 2-split (a = ah + 2^-11 al', 3 K-segments,
// eps ~ 2^-22 data-level, one-shot => safe vs the 2% threshold; np-ref floor 8.1e31).
// R-power chain (G build, squarings, tree) stays fp32 VALU: map errors compound.

namespace {

constexpr int BATCH = 32;
constexpr int T = 2048;
constexpr int U = 1024;

constexpr int LJ = 8;               // chunk length
constexpr int CJ = T / LJ;          // 256 chunks
constexpr int MJ = CJ * BATCH;      // 8192 aggregate rows
constexpr int KSEG = LJ * U;        // 8192 K per split-segment

typedef _Float16 f16;
typedef _Float16 f16x8 __attribute__((ext_vector_type(8)));
typedef _Float16 f16x4 __attribute__((ext_vector_type(4)));
typedef float f32x4 __attribute__((ext_vector_type(4)));

__device__ inline void gload16(const void* gsrc, void* ldst) {
    __builtin_amdgcn_global_load_lds(
        (const __attribute__((address_space(1))) unsigned int*)gsrc,
        (__attribute__((address_space(3))) unsigned int*)ldst,
        16, 0, 0);
}

// ---------------- split x: xh = f16(x), xl = f16((x - xh) * 2^11) ----------------
__global__ __launch_bounds__(256)
void split_x(const float* __restrict__ x, f16* __restrict__ xh, f16* __restrict__ xl,
             long n4)
{
    long i = (long)blockIdx.x * 256 + threadIdx.x;
    const long stride = (long)gridDim.x * 256;
    for (; i < n4; i += stride) {
        const float4 v = *(const float4*)(x + i * 4);
        f16x4 h, l;
        h.x = (f16)v.x; l.x = (f16)((v.x - (float)h.x) * 2048.0f);
        h.y = (f16)v.y; l.y = (f16)((v.y - (float)h.y) * 2048.0f);
        h.z = (f16)v.z; l.z = (f16)((v.z - (float)h.z) * 2048.0f);
        h.w = (f16)v.w; l.w = (f16)((v.w - (float)h.w) * 2048.0f);
        *(f16x4*)(xh + i * 4) = h;
        *(f16x4*)(xl + i * 4) = l;
    }
}

// ------------- transpose+split G[8192][1024] -> GhT/GlT [1024][8192] -------------
__global__ __launch_bounds__(256)
void tsplit_g(const float* __restrict__ G, f16* __restrict__ GhT, f16* __restrict__ GlT)
{
    __shared__ float tile[32][33];
    const int t = threadIdx.x;
    const int k0 = blockIdx.x * 32;   // G row (k) tile
    const int u0 = blockIdx.y * 32;   // G col (u) tile
    {
        const int r = t >> 3, c4 = (t & 7) << 2;
        const float4 v = *(const float4*)(G + (size_t)(k0 + r) * U + u0 + c4);
        tile[r][c4 + 0] = v.x; tile[r][c4 + 1] = v.y;
        tile[r][c4 + 2] = v.z; tile[r][c4 + 3] = v.w;
    }
    __syncthreads();
    {
        const int c = t >> 3, r4 = (t & 7) << 2;
        f16x4 h, l;
        float v0 = tile[r4 + 0][c], v1 = tile[r4 + 1][c],
              v2 = tile[r4 + 2][c], v3 = tile[r4 + 3][c];
        h.x = (f16)v0; l.x = (f16)((v0 - (float)h.x) * 2048.0f);
        h.y = (f16)v1; l.y = (f16)((v1 - (float)h.y) * 2048.0f);
        h.z = (f16)v2; l.z = (f16)((v2 - (float)h.z) * 2048.0f);
        h.w = (f16)v3; l.w = (f16)((v3 - (float)h.w) * 2048.0f);
        const size_t o = (size_t)(u0 + c) * KSEG + k0 + r4;
        *(f16x4*)(GhT + o) = h;
        *(f16x4*)(GlT + o) = l;
    }
}

// ---------------- main MFMA GEMM: g0[8192][1024] = Xgather @ G (fp16 2-split) ----
// 128x128 tile, 4 waves (2x2, each 64x64 = 4x4 frags of 16x16x32_f16), BK=64.
// Segments: (xh,GlT) + (xl,GhT) -> acc; acc *= 2^-11; + (xh,GhT).
__global__ __launch_bounds__(256)
void main_mfma(const f16* __restrict__ xh, const f16* __restrict__ xl,
               const f16* __restrict__ GhT, const f16* __restrict__ GlT,
               float* __restrict__ g0)
{
    __shared__ __align__(16) f16 As[128 * 64];
    __shared__ __align__(16) f16 Bs[128 * 64];

    const int tid  = threadIdx.x;
    const int lane = tid & 63;
    const int w    = tid >> 6;
    const int wm = w >> 1, wn = w & 1;
    const int c0 = blockIdx.x * 128;   // col block (8)
    const int r0 = blockIdx.y * 128;   // row block (64)

    // staging: per wave-call q, cid = w + 4q covers 1 KiB of the tile.
    // tile row m = cid*8 + (lane>>3); 16B chunk (lane&7), pre-swizzled by (m&7).
    const int swzc = ((lane & 7) ^ ((lane >> 3) & 7)) << 4;  // byte offset of chunk
    size_t aoff[4], boff[4];
    int ldsoff[4];
    #pragma unroll
    for (int q = 0; q < 4; ++q) {
        const int cid = w + 4 * q;
        const int m = cid * 8 + (lane >> 3);
        const int arow = r0 + m;
        // x-gather row: base elem = ((b*T) + c*LJ) * U,  b=arow&31, c=arow>>5
        const size_t xbase = ((size_t)(arow & 31) * T + (size_t)(arow >> 5) * LJ) * U;
        aoff[q] = (xbase << 1) + swzc;                 // bytes
        boff[q] = ((size_t)(c0 + m) << 14) + swzc;     // col * 8192 * 2B
        ldsoff[q] = cid * 512;                          // f16 elements (1 KiB)
    }

    f32x4 acc[4][4];
    #pragma unroll
    for (int mi = 0; mi < 4; ++mi)
        #pragma unroll
        for (int ni = 0; ni < 4; ++ni)
            acc[mi][ni] = (f32x4){0.f, 0.f, 0.f, 0.f};

    #pragma unroll 1
    for (int seg = 0; seg < 3; ++seg) {
        const f16* __restrict__ Aseg = (seg == 1) ? xl : xh;
        const f16* __restrict__ Bseg = (seg == 0) ? GlT : GhT;

        #pragma unroll 1
        for (int kt = 0; kt < KSEG / 64; ++kt) {
            const size_t kb = (size_t)kt << 7;   // 64 k * 2B
            #pragma unroll
            for (int q = 0; q < 4; ++q) {
                gload16((const char*)Aseg + aoff[q] + kb, &As[ldsoff[q]]);
                gload16((const char*)Bseg + boff[q] + kb, &Bs[ldsoff[q]]);
            }
            __syncthreads();   // drains vmcnt before barrier (compiler-enforced)

            #pragma unroll
            for (int ks = 0; ks < 2; ++ks) {
                f16x8 af[4], bf[4];
                #pragma unroll
                for (int mi = 0; mi < 4; ++mi) {
                    const int row = wm * 64 + mi * 16 + (lane & 15);
                    int byte = row * 128 + (ks * 32 + (lane >> 4) * 8) * 2;
                    byte ^= (row & 7) << 4;
                    af[mi] = *(const f16x8*)((const char*)As + byte);
                }
                #pragma unroll
                for (int ni = 0; ni < 4; ++ni) {
                    const int rowb = wn * 64 + ni * 16 + (lane & 15);
                    int byte = rowb * 128 + (ks * 32 + (lane >> 4) * 8) * 2;
                    byte ^= (rowb & 7) << 4;
                    bf[ni] = *(const f16x8*)((const char*)Bs + byte);
                }
                #pragma unroll
                for (int mi = 0; mi < 4; ++mi)
                    #pragma unroll
                    for (int ni = 0; ni < 4; ++ni)
                        acc[mi][ni] = __builtin_amdgcn_mfma_f32_16x16x32_f16(
                            af[mi], bf[ni], acc[mi][ni], 0, 0, 0);
            }
            __syncthreads();
        }

        if (seg == 1) {
            #pragma unroll
            for (int mi = 0; mi < 4; ++mi)
                #pragma unroll
                for (int ni = 0; ni < 4; ++ni)
                    #pragma unroll
                    for (int r = 0; r < 4; ++r)
                        acc[mi][ni][r] *= (1.0f / 2048.0f);
        }
    }

    // epilogue: C/D layout col=lane&15, row=(lane>>4)*4+reg  [m89-verified]
    #pragma unroll
    for (int mi = 0; mi < 4; ++mi) {
        #pragma unroll
        for (int reg = 0; reg < 4; ++reg) {
            const int row = r0 + wm * 64 + mi * 16 + ((lane >> 4) << 2) + reg;
            #pragma unroll
            for (int ni = 0; ni < 4; ++ni) {
                const int col = c0 + wn * 64 + ni * 16 + (lane & 15);
                g0[(size_t)row * U + col] = acc[mi][ni][reg];
            }
        }
    }
}

// ---------------- fp32 VALU GEMM (G build / tree / squarings / fallback) ---------
struct Desc {
    const float* A;
    const float* B;
    float* C;
    int M;
    int K;
    int mode;   // 0: C=A@B   1: x-gather A   2: C+=A@B   3: tree combine
};

__global__ __launch_bounds__(256, 2)
void gemm128(Desc d0, Desc d1)
{
    Desc d = (blockIdx.z == 0) ? d0 : d1;
    const int row0 = blockIdx.x * 128;
    if (row0 >= d.M) return;
    const int col0 = blockIdx.y * 64;

    __shared__ float As[2][16][128];
    __shared__ float Bs[2][16][64];

    const int tid = threadIdx.x;
    const int tx = tid & 15;
    const int ty = tid >> 4;
    const int la_row = tid & 127;
    const int la_k   = (tid >> 7) << 3;
    const int lb_k   = tid >> 4;
    const int lb_c   = (tid & 15) << 2;

    int ar = row0 + la_row;
    if (ar >= d.M) ar = d.M - 1;
    const float* aP;
    if (d.mode == 1) {
        aP = d.A + ((size_t)((ar & 31) * T + ((ar >> 5) * LJ)) << 10);
    } else if (d.mode == 3) {
        aP = d.A + ((size_t)(((ar >> 5) << 6) + (ar & 31)) << 10);
    } else {
        aP = d.A + ((size_t)ar << 10);
    }
    aP += la_k;
    const float* bP = d.B + ((size_t)lb_k << 10) + col0 + lb_c;

    float acc[8][4];
    #pragma unroll
    for (int r = 0; r < 8; ++r)
        #pragma unroll
        for (int c = 0; c < 4; ++c) acc[r][c] = 0.0f;

    {
        const float4 a0 = *(const float4*)(aP);
        const float4 a1 = *(const float4*)(aP + 4);
        const float4 b0 = *(const float4*)(bP);
        As[0][la_k+0][la_row]=a0.x; As[0][la_k+1][la_row]=a0.y;
        As[0][la_k+2][la_row]=a0.z; As[0][la_k+3][la_row]=a0.w;
        As[0][la_k+4][la_row]=a1.x; As[0][la_k+5][la_row]=a1.y;
        As[0][la_k+6][la_row]=a1.z; As[0][la_k+7][la_row]=a1.w;
        *(float4*)&Bs[0][lb_k][lb_c] = b0;
    }
    __syncthreads();

    const int NT = d.K >> 4;
    int buf = 0;
    #pragma unroll 1
    for (int kt = 0; kt < NT; ++kt) {
        float4 na0, na1, nb0;
        const bool more = (kt + 1 < NT);
        if (more) {
            const float* ap = aP + ((kt + 1) << 4);
            na0 = *(const float4*)(ap);
            na1 = *(const float4*)(ap + 4);
            nb0 = *(const float4*)(bP + ((size_t)((kt + 1) << 4) << 10));
        }

        #pragma unroll
        for (int kk = 0; kk < 16; ++kk) {
            const float4 a0 = *(const float4*)&As[buf][kk][ty << 3];
            const float4 a1 = *(const float4*)&As[buf][kk][(ty << 3) + 4];
            const float4 bv = *(const float4*)&Bs[buf][kk][tx << 2];
            const float ar8[8] = {a0.x,a0.y,a0.z,a0.w,a1.x,a1.y,a1.z,a1.w};
            const float bc4[4] = {bv.x,bv.y,bv.z,bv.w};
            #pragma unroll
            for (int r = 0; r < 8; ++r)
                #pragma unroll
                for (int c = 0; c < 4; ++c)
                    acc[r][c] = fmaf(ar8[r], bc4[c], acc[r][c]);
        }

        if (more) {
            As[buf^1][la_k+0][la_row]=na0.x; As[buf^1][la_k+1][la_row]=na0.y;
            As[buf^1][la_k+2][la_row]=na0.z; As[buf^1][la_k+3][la_row]=na0.w;
            As[buf^1][la_k+4][la_row]=na1.x; As[buf^1][la_k+5][la_row]=na1.y;
            As[buf^1][la_k+6][la_row]=na1.z; As[buf^1][la_k+7][la_row]=na1.w;
            *(float4*)&Bs[buf^1][lb_k][lb_c] = nb0;
        }
        __syncthreads();
        buf ^= 1;
    }

    #pragma unroll
    for (int r = 0; r < 8; ++r) {
        const int row = row0 + (ty << 3) + r;
        if (row < d.M) {
            float4 o;
            o.x = acc[r][0]; o.y = acc[r][1]; o.z = acc[r][2]; o.w = acc[r][3];
            float* cp = d.C + ((size_t)row << 10) + col0 + (tx << 2);
            if (d.mode == 2) {
                const float4 cv = *(const float4*)cp;
                o.x += cv.x; o.y += cv.y; o.z += cv.z; o.w += cv.w;
            } else if (d.mode == 3) {
                const int arow2 = ((row >> 5) << 6) + (row & 31) + 32;
                const float4 ad = *(const float4*)(d.A + ((size_t)arow2 << 10) + col0 + (tx << 2));
                o.x += ad.x; o.y += ad.y; o.z += ad.z; o.w += ad.w;
            }
            *(float4*)cp = o;
        }
    }
}

} // namespace

extern "C" void kernel_launch(void* const* d_in, const int* in_sizes, int n_in,
                              void* d_out, int out_size, void* d_ws, size_t ws_size,
                              hipStream_t stream) {
    const float* x  = (const float*)d_in[0];   // [32, 2048, 1024]
    const float* h0 = (const float*)d_in[1];   // [32, 1024]
    const float* W  = (const float*)d_in[2];   // [1024, 1024]
    const float* R  = (const float*)d_in[3];   // [1024, 1024]
    float* out = (float*)d_out;                // [32, 1024]

    // ws layout (394,264,576 B total for primary path)
    float* G  = (float*)d_ws;                       // [8192][1024] f32
    float* g0 = G  + (size_t)LJ * U * U;            // [8192][1024] f32
    float* g1 = g0 + (size_t)MJ * U;                // [4096][1024] f32
    float* QA = g1 + (size_t)(MJ / 2) * U;          // [1024][1024] f32
    float* QB = QA + (size_t)U * U;
    f16* xh  = (f16*)(QB + (size_t)U * U);          // [64M] f16
    f16* xl  = xh + (size_t)BATCH * T * U;
    f16* GhT = xl + (size_t)BATCH * T * U;          // [1024][8192] f16
    f16* GlT = GhT + (size_t)U * KSEG;
    const size_t need = (size_t)((char*)(GlT + (size_t)U * KSEG) - (char*)d_ws);

    Desc dz; dz.A = nullptr; dz.B = nullptr; dz.C = nullptr; dz.M = 0; dz.K = 16; dz.mode = 0;
    auto launch2 = [&](Desc a, Desc b) {
        const int mx = (a.M > b.M) ? a.M : b.M;
        dim3 grid((unsigned)((mx + 127) / 128), (unsigned)(U / 64), 2);
        gemm128<<<grid, dim3(256), 0, stream>>>(a, b);
    };
    auto D = [](const float* A, const float* B, float* C, int M, int K, int mode) {
        Desc d; d.A = A; d.B = B; d.C = C; d.M = M; d.K = K; d.mode = mode; return d;
    };
    auto Gs = [&](int s) { return G + (size_t)s * U * U; };

    if (ws_size >= need) {
        // 0) split x (independent)
        split_x<<<2048, 256, 0, stream>>>(x, xh, xl, (long)BATCH * T * U / 4);

        // 1) G build (fp32) fused with R-power squarings
        hipMemcpyAsync(Gs(LJ - 1), W, (size_t)U * U * sizeof(float),
                       hipMemcpyDeviceToDevice, stream);
        launch2(D(Gs(7), R,  Gs(6), U,     U, 0), D(R,  R,  QA, U, U, 0));  // WR ; R2
        launch2(D(Gs(6), QA, Gs(4), 2 * U, U, 0), D(QA, QA, QB, U, U, 0));  // WR2,3 ; R4
        launch2(D(Gs(4), QB, Gs(0), 4 * U, U, 0), D(QB, QB, QA, U, U, 0));  // WR4..7 ; R8

        // 2) transpose+split G -> GhT/GlT [1024][8192]
        tsplit_g<<<dim3(KSEG / 32, U / 32), 256, 0, stream>>>(G, GhT, GlT);

        // 3) main MFMA GEMM
        main_mfma<<<dim3(U / 128, MJ / 128), 256, 0, stream>>>(xh, xl, GhT, GlT, g0);

        // 4) inject h0: g0[0:32] += h0 @ R^8 (QA)
        launch2(D(h0, QA, g0, BATCH, U, 2), dz);

        // 5) tree combine: 8 levels, Q_l = R^(8*2^l) starting at QA = R^8
        float* q  = QA;
        float* qn = QB;
        float* cur = g0;
        float* nxt = g1;
        for (int l = 0; l < 8; ++l) {
            const int M = BATCH * ((CJ / 2) >> l);    // 4096 ... 32
            float* dst = (l == 7) ? out : nxt;
            Desc dc = D(cur, q, dst, M, U, 3);
            Desc ds = dz;
            if (l < 7) ds = D(q, q, qn, U, U, 0);
            launch2(dc, ds);
            if (l < 7) { float* t = q; q = qn; qn = t; }
            float* t2 = cur; cur = nxt; nxt = t2;
        }
    } else {
        // ---------------- fallback: proven R3 fp32 path (needs ~88 MB) ----------
        float* Gf  = (float*)d_ws;
        float* g0f = Gf + (size_t)LJ * U * U;
        float* g1f = g0f + (size_t)MJ * U;
        float* QAf = g1f + (size_t)(MJ / 2) * U;
        float* QBf = QAf + (size_t)U * U;
        auto Gfs = [&](int s) { return Gf + (size_t)s * U * U; };

        hipMemcpyAsync(Gfs(LJ - 1), W, (size_t)U * U * sizeof(float),
                       hipMemcpyDeviceToDevice, stream);
        launch2(D(Gfs(7), R,   Gfs(6), U,     U, 0), D(R,   R,   QAf, U, U, 0));
        launch2(D(Gfs(6), QAf, Gfs(4), 2 * U, U, 0), D(QAf, QAf, QBf, U, U, 0));
        launch2(D(Gfs(4), QBf, Gfs(0), 4 * U, U, 0), D(QBf, QBf, QAf, U, U, 0));

        launch2(D(x, Gf, g0f, MJ, LJ * U, 1), dz);
        launch2(D(h0, QAf, g0f, BATCH, U, 2), dz);

        float* q  = QAf;
        float* qn = QBf;
        float* cur = g0f;
        float* nxt = g1f;
        for (int l = 0; l < 8; ++l) {
            const int M = BATCH * ((CJ / 2) >> l);
            float* dst = (l == 7) ? out : nxt;
            Desc dc = D(cur, q, dst, M, U, 3);
            Desc ds = dz;
            if (l < 7) ds = D(q, q, qn, U, U, 0);
            launch2(dc, ds);
            if (l < 7) { float* t = q; q = qn; qn = t; }
            float* t2 = cur; cur = nxt; nxt = t2;
        }
    }
    (void)in_sizes; (void)n_in; (void)out_size; (void)ws_size;
}